// Round 12
// baseline (3283.455 us; speedup 1.0000x reference)
//
#include <hip/hip_runtime.h>
#include <hip/hip_fp16.h>
#include <stdint.h>

#define NBATCH 32
#define NPTS   65536
#define MCENT  2048
#define BPB    8                 // blocks per batch (proven topology)
#define THREADS 1024
#define CHUNK  (NPTS / BPB)      // 8192 points per block
#define WPT    (CHUNK / THREADS) // 8 points per thread
#define NPAIR  (WPT / 2)
#define NWAVE  (THREADS / 64)    // 16 waves
#define GPW    2                 // groups (half-waves) per wave
#define NGRP   (NWAVE * GPW)     // 32 groups per block (256 pts each)
#define GTOT   (BPB * NGRP)      // 256 groups per batch
#define TMAX   64
#define BOXTAG 0xBBBBu

typedef unsigned long long u64;
typedef uint32_t u32;
typedef uint16_t u16;
typedef float v2f __attribute__((ext_vector_type(2)));

static __device__ __forceinline__ u32 fbits(float f) { union { float f; u32 u; } c; c.f = f; return c.u; }
static __device__ __forceinline__ float bitsf(u32 u) { union { u32 u; float f; } c; c.u = u; return c.f; }

// wave-wide max of nonneg u32 via DPP row reduce (proven R4..R11)
static __device__ __forceinline__ u32 wave_max_u32(u32 v) {
#define STEP(CTRL) { const u32 o = (u32)__builtin_amdgcn_update_dpp(0, (int)v, CTRL, 0xF, 0xF, true); v = o > v ? o : v; }
    STEP(0x111) STEP(0x112) STEP(0x114) STEP(0x118) STEP(0x142) STEP(0x143)
#undef STEP
    return (u32)__builtin_amdgcn_readlane((int)v, 63);
}
// fused dual wave-max (two independent DPP chains interleave -> ~1 chain latency)
static __device__ __forceinline__ void wave_max2_u32(u32 &a, u32 &b) {
#define STEP2(CTRL) { const u32 oa = (u32)__builtin_amdgcn_update_dpp(0, (int)a, CTRL, 0xF, 0xF, true); \
                      const u32 ob = (u32)__builtin_amdgcn_update_dpp(0, (int)b, CTRL, 0xF, 0xF, true); \
                      a = oa > a ? oa : a; b = ob > b ? ob : b; }
    STEP2(0x111) STEP2(0x112) STEP2(0x114) STEP2(0x118) STEP2(0x142) STEP2(0x143)
#undef STEP2
    a = (u32)__builtin_amdgcn_readlane((int)a, 63);
    b = (u32)__builtin_amdgcn_readlane((int)b, 63);
}

// conservative fp16 rounding (lo: toward -inf, hi: toward +inf) so the
// half-precision box always CONTAINS the fp32 box.
static __device__ __forceinline__ u16 h_down(float x) {
    __half h = __float2half(x); float f = __half2float(h);
    u16 bb = __half_as_ushort(h);
    if (f > x) { if (bb == 0x0000u) bb = 0x8001u; else if (bb & 0x8000u) bb += 1; else bb -= 1; }
    return bb;
}
static __device__ __forceinline__ u16 h_up(float x) {
    __half h = __float2half(x); float f = __half2float(h);
    u16 bb = __half_as_ushort(h);
    if (f < x) { if (bb == 0x8000u) bb = 0x0001u; else if (bb & 0x8000u) bb -= 1; else bb += 1; }
    return bb;
}
static __device__ __forceinline__ u32 spread4(int v) {   // 4 bits -> every 3rd bit
    return (u32)((v & 1) | ((v & 2) << 2) | ((v & 4) << 4) | ((v & 8) << 6));
}

// ============================================================================
// SPATIAL kernel: proven R5/R11 round skeleton + Morton-sorted groups +
// dynamic box-crush tau.
//
// Output-invariance: the winner SEQUENCE is grouping-independent (every
// accepted winner is the exact global argmax with first-occurrence tie
// semantics; tau only decides when a round bails). Sorting/grouping/boxes
// affect SPEED only. Distance chain everywhere: subs, then
// fma(dz,dz, fma(dx,dx, mul(dy,dy))), chronological fminf — bit-identical.
//
// Dynamic tau proof: hidden h in group g (not in published top-3):
//   cur(h) = min(pub(h), min_{w accepted this round} d2(h,w))
//          <= min(third_g, min_w maxdist2(w, box_g))        [h inside box_g]
// tau = max_g of that bound; accept iff winner value STRICTLY > tau
// (hidden points can then neither beat nor tie). box_g is computed from the
// ACTUAL member registers (containment holds even if the sort misorders)
// and published once with conservative fp16 rounding. Bitonic sort is
// deterministic -> boxes identical across graph replays -> stale workspace
// content equals fresh content (benign).
//
// Failed-structure ledger (do not revisit): hot-spin consume (R6, 2.4x);
// 2-blocks/CU TLP (R7, null); sleep-consume (R9, +14%); replicated
// selection (R10, 2x, issue-bound).
// ============================================================================
__global__ __launch_bounds__(THREADS, 1) void fps_spatial(
    const float* __restrict__ xyz,
    float* __restrict__ out,
    u64* __restrict__ slots)
{
    constexpr int TOPK  = 3;
    constexpr int POOLW = BPB * NGRP * TOPK;   // 768 words/batch/parity
    constexpr int WPL   = POOLW / 64;          // 12 words/lane

    const int t = threadIdx.x;
    const int b = blockIdx.x >> 3;
    const int j = blockIdx.x & 7;
    const float* base = xyz + (size_t)b * NPTS * 3;
    const int p0 = j * CHUNK;
    const int wave = t >> 6;
    const int lane = t & 63;

    __shared__ u32   skey[CHUNK];          // 32 KB (startup only)
    __shared__ float boxf[GTOT * 6];       // 6 KB fp32 boxes (all 256 groups)
    __shared__ float wcx[TMAX], wcy[TMAX], wcz[TMAX];
    __shared__ int   wcnt;
    __shared__ float red[6 * NWAVE];

    // ---- startup 1: chunk AABB (deterministic reduction) ----
    float mnx = 3e38f, mny = 3e38f, mnz = 3e38f;
    float mxx = -3e38f, mxy = -3e38f, mxz = -3e38f;
    for (int q = 0; q < WPT; ++q) {
        const int p = p0 + q * THREADS + t;
        const float x = base[(size_t)p * 3 + 0];
        const float y = base[(size_t)p * 3 + 1];
        const float z = base[(size_t)p * 3 + 2];
        mnx = fminf(mnx, x); mxx = fmaxf(mxx, x);
        mny = fminf(mny, y); mxy = fmaxf(mxy, y);
        mnz = fminf(mnz, z); mxz = fmaxf(mxz, z);
    }
#pragma unroll
    for (int m = 1; m <= 32; m <<= 1) {
        mnx = fminf(mnx, __shfl_xor(mnx, m)); mxx = fmaxf(mxx, __shfl_xor(mxx, m));
        mny = fminf(mny, __shfl_xor(mny, m)); mxy = fmaxf(mxy, __shfl_xor(mxy, m));
        mnz = fminf(mnz, __shfl_xor(mnz, m)); mxz = fmaxf(mxz, __shfl_xor(mxz, m));
    }
    if (lane == 0) {
        red[wave] = mnx; red[NWAVE + wave] = mny; red[2 * NWAVE + wave] = mnz;
        red[3 * NWAVE + wave] = mxx; red[4 * NWAVE + wave] = mxy; red[5 * NWAVE + wave] = mxz;
    }
    __syncthreads();
    mnx = red[0]; mny = red[NWAVE]; mnz = red[2 * NWAVE];
    mxx = red[3 * NWAVE]; mxy = red[4 * NWAVE]; mxz = red[5 * NWAVE];
    for (int i = 1; i < NWAVE; ++i) {
        mnx = fminf(mnx, red[i]); mny = fminf(mny, red[NWAVE + i]); mnz = fminf(mnz, red[2 * NWAVE + i]);
        mxx = fmaxf(mxx, red[3 * NWAVE + i]); mxy = fmaxf(mxy, red[4 * NWAVE + i]); mxz = fmaxf(mxz, red[5 * NWAVE + i]);
    }
    const float sx = 16.0f / (mxx - mnx + 1e-20f);
    const float sy = 16.0f / (mxy - mny + 1e-20f);
    const float sz = 16.0f / (mxz - mnz + 1e-20f);
    __syncthreads();   // red reuse-free; keys next

    // ---- startup 2: Morton keys (12-bit) | local idx (13-bit) ----
    for (int q = 0; q < WPT; ++q) {
        const int li = q * THREADS + t;
        const int p = p0 + li;
        const float x = base[(size_t)p * 3 + 0];
        const float y = base[(size_t)p * 3 + 1];
        const float z = base[(size_t)p * 3 + 2];
        int qx = (int)((x - mnx) * sx); qx = qx < 0 ? 0 : (qx > 15 ? 15 : qx);
        int qy = (int)((y - mny) * sy); qy = qy < 0 ? 0 : (qy > 15 ? 15 : qy);
        int qz = (int)((z - mnz) * sz); qz = qz < 0 ? 0 : (qz > 15 ? 15 : qz);
        const u32 m12 = spread4(qx) | (spread4(qy) << 1) | (spread4(qz) << 2);
        skey[li] = (m12 << 13) | (u32)li;
    }
    __syncthreads();

    // ---- startup 3: bitonic sort (deterministic, permutation-safe) ----
    for (int k = 2; k <= CHUNK; k <<= 1) {
        for (int jj = k >> 1; jj >= 1; jj >>= 1) {
            for (int q = 0; q < WPT; ++q) {
                const int i = q * THREADS + t;
                const int ix = i ^ jj;
                if (ix > i) {
                    const u32 a = skey[i], c = skey[ix];
                    const bool up = ((i & k) == 0);
                    if ((a > c) == up) { skey[i] = c; skey[ix] = a; }
                }
            }
            __syncthreads();
        }
    }

    // ---- startup 4: gather sorted coords into registers ----
    v2f px2[NPAIR], py2[NPAIR], pz2[NPAIR];
    float pd[WPT];
    u32 invp[WPT];               // 0xFFFF ^ original global idx
    for (int q = 0; q < WPT; ++q) {
        const int slot = t * WPT + q;                 // half-wave-contiguous
        const int li = (int)(skey[slot] & 0x1FFFu);
        const int p = p0 + li;
        px2[q >> 1][q & 1] = base[(size_t)p * 3 + 0];
        py2[q >> 1][q & 1] = base[(size_t)p * 3 + 1];
        pz2[q >> 1][q & 1] = base[(size_t)p * 3 + 2];
        pd[q] = 1e10f;
        invp[q] = 0xFFFFu ^ (u32)p;
    }

    // ---- startup 5: group AABB from the ACTUAL held registers ----
    float blx = 3e38f, bly = 3e38f, blz = 3e38f;
    float bhx = -3e38f, bhy = -3e38f, bhz = -3e38f;
#pragma unroll
    for (int q = 0; q < WPT; ++q) {
        const float x = px2[q >> 1][q & 1], y = py2[q >> 1][q & 1], z = pz2[q >> 1][q & 1];
        blx = fminf(blx, x); bhx = fmaxf(bhx, x);
        bly = fminf(bly, y); bhy = fmaxf(bhy, y);
        blz = fminf(blz, z); bhz = fmaxf(bhz, z);
    }
#pragma unroll
    for (int m = 1; m <= 16; m <<= 1) {   // half-wave reduce
        blx = fminf(blx, __shfl_xor(blx, m)); bhx = fmaxf(bhx, __shfl_xor(bhx, m));
        bly = fminf(bly, __shfl_xor(bly, m)); bhy = fmaxf(bhy, __shfl_xor(bhy, m));
        blz = fminf(blz, __shfl_xor(blz, m)); bhz = fmaxf(bhz, __shfl_xor(bhz, m));
    }
    u64* const boxw = slots + (size_t)2 * NBATCH * POOLW + (size_t)b * (GTOT * 2);
    if ((lane & 31) == 0) {
        const int g = j * NGRP + wave * GPW + (lane >> 5);    // global group id
        const u64 lo = ((u64)h_down(blx)) | ((u64)h_down(bly) << 16) | ((u64)h_down(blz) << 32);
        const u64 hi = ((u64)h_up(bhx))  | ((u64)h_up(bhy)  << 16) | ((u64)h_up(bhz)  << 32);
        __hip_atomic_store(&boxw[g * 2 + 0], (lo << 16) | BOXTAG, __ATOMIC_RELAXED, __HIP_MEMORY_SCOPE_AGENT);
        __hip_atomic_store(&boxw[g * 2 + 1], (hi << 16) | BOXTAG, __ATOMIC_RELAXED, __HIP_MEMORY_SCOPE_AGENT);
    }
    if (t == 0) {
        const float cx = base[0], cy = base[1], cz = base[2];
        wcx[0] = cx; wcy[0] = cy; wcz[0] = cz; wcnt = 1;
        if (j == 0) {
            float* o = out + (size_t)b * MCENT * 3;
            o[0] = cx; o[1] = cy; o[2] = cz;
        }
    }
    if (wave == 0) {   // poll all 512 box words; expand to fp32 LDS
        u64 v[8]; int ok;
        do {
#pragma unroll
            for (int r = 0; r < 8; ++r)
                v[r] = __hip_atomic_load(&boxw[lane + 64 * r], __ATOMIC_RELAXED, __HIP_MEMORY_SCOPE_AGENT);
            ok = 1;
#pragma unroll
            for (int r = 0; r < 8; ++r) ok &= ((u32)(v[r] & 0xFFFFull) == BOXTAG);
        } while (!__all(ok));
#pragma unroll
        for (int r = 0; r < 8; ++r) {
            const int wi = lane + 64 * r;
            const u64 pay = v[r] >> 16;
            const int g = wi >> 1, half = wi & 1;
            boxf[g * 6 + half * 3 + 0] = __half2float(__ushort_as_half((u16)(pay & 0xFFFFu)));
            boxf[g * 6 + half * 3 + 1] = __half2float(__ushort_as_half((u16)((pay >> 16) & 0xFFFFu)));
            boxf[g * 6 + half * 3 + 2] = __half2float(__ushort_as_half((u16)((pay >> 32) & 0xFFFFu)));
        }
    }

    // ==================== round loop (proven R5/R11 skeleton) ===============
    int C = 0;
    for (int s = 1; ; ++s) {
        __syncthreads();
        const int tn = wcnt;
        C += tn;
        if (C >= MCENT) break;

        // Phase A (packed fp32, bit-exact per half)
        for (int tt = 0; tt < tn; ++tt) {
            const float cx = wcx[tt], cy = wcy[tt], cz = wcz[tt];
            const v2f cx2 = { cx, cx }, cy2 = { cy, cy }, cz2 = { cz, cz };
#pragma unroll
            for (int q = 0; q < NPAIR; ++q) {
                const v2f dx2 = px2[q] - cx2;
                const v2f dy2 = py2[q] - cy2;
                const v2f dz2 = pz2[q] - cz2;
                const v2f t0 = dy2 * dy2;
                const v2f t1 = __builtin_elementwise_fma(dx2, dx2, t0);
                const v2f t2 = __builtin_elementwise_fma(dz2, dz2, t1);
                pd[2 * q + 0] = fminf(pd[2 * q + 0], t2.x);
                pd[2 * q + 1] = fminf(pd[2 * q + 1], t2.y);
            }
        }

        // per-lane top-3 (keys carry ORIGINAL global idx, inverted)
        u64 k1 = 0, k2 = 0, k3 = 0;
#pragma unroll
        for (int q = 0; q < WPT; ++q) {
            const u64 kk = ((u64)fbits(pd[q]) << 16) | (u64)invp[q];
            if (kk > k1)      { k3 = k2; k2 = k1; k1 = kk; }
            else if (kk > k2) { k3 = k2; k2 = kk; }
            else if (kk > k3) { k3 = kk; }
        }
#pragma unroll
        for (int m = 1; m <= 16; m <<= 1) {
            const u64 o1 = __shfl_xor(k1, m);
            const u64 o2 = __shfl_xor(k2, m);
            const u64 o3 = __shfl_xor(k3, m);
            u64 m1, m2, m3;
            if (o1 > k1) {
                m1 = o1;
                if (o2 > k1) { m2 = o2; m3 = (o3 > k1) ? o3 : k1; }
                else         { m2 = k1; m3 = (o2 > k2) ? o2 : k2; }
            } else {
                m1 = k1;
                if (o1 > k2) { m2 = o1; m3 = (o2 > k2) ? o2 : k2; }
                else         { m2 = k2; m3 = (o1 > k3) ? o1 : k3; }
            }
            k1 = m1; k2 = m2; k3 = m3;
        }

        u64* const bb = slots + ((size_t)(s & 1) * NBATCH + b) * POOLW;
        const u32 tag = (u32)s & 0xFFFFu;

        if ((lane & 31) == 0) {
            const int g = wave * GPW + (lane >> 5);
            u64* const gw = &bb[j * (NGRP * TOPK) + g * TOPK];
            __hip_atomic_store(&gw[0], (k1 << 16) | tag, __ATOMIC_RELAXED, __HIP_MEMORY_SCOPE_AGENT);
            __hip_atomic_store(&gw[1], (k2 << 16) | tag, __ATOMIC_RELAXED, __HIP_MEMORY_SCOPE_AGENT);
            __hip_atomic_store(&gw[2], (k3 << 16) | tag, __ATOMIC_RELAXED, __HIP_MEMORY_SCOPE_AGENT);
        }

        if (wave == 0) {
            u64 w[WPL]; int ok;
            do {
#pragma unroll
                for (int r = 0; r < WPL; ++r)
                    w[r] = __hip_atomic_load(&bb[lane + 64 * r], __ATOMIC_RELAXED, __HIP_MEMORY_SCOPE_AGENT);
                ok = 1;
#pragma unroll
                for (int r = 0; r < WPL; ++r)
                    ok &= ((u32)(w[r] & 0xFFFFull) == tag);
            } while (!__all(ok));

            u32 pv[WPL], pi[WPL];
            float ex[WPL], ey[WPL], ez[WPL];
#pragma unroll
            for (int r = 0; r < WPL; ++r) {
                pv[r] = (u32)(w[r] >> 32);
                pi[r] = ((u32)w[r] >> 16) & 0xFFFFu;
                const int gi = (int)(0xFFFFu ^ pi[r]);
                ex[r] = base[(size_t)gi * 3 + 0];
                ey[r] = base[(size_t)gi * 3 + 1];
                ez[r] = base[(size_t)gi * 3 + 2];
            }

            // dynamic-tau state: lane owns groups 4*lane..4*lane+3
            u32 third[4]; float cr[4];
#pragma unroll
            for (int i = 0; i < 4; ++i) {
                const u64 tw = __hip_atomic_load(&bb[(4 * lane + i) * 3 + 2],
                                                 __ATOMIC_RELAXED, __HIP_MEMORY_SCOPE_AGENT);
                third[i] = (u32)(tw >> 32);
                cr[i] = 3e38f;
            }
            u32 lb = 0;
#pragma unroll
            for (int i = 0; i < 4; ++i) lb = third[i] > lb ? third[i] : lb;

            int tc = 0;
            while (1) {
                u32 lv = 0;
#pragma unroll
                for (int r = 0; r < WPL; ++r) lv = pv[r] > lv ? pv[r] : lv;
                u32 vmax = lv, tau = lb;
                wave_max2_u32(vmax, tau);
                if (tc > 0 && vmax <= tau) break;    // strict > required

                u32 ic = 0;
#pragma unroll
                for (int r = 0; r < WPL; ++r)
                    ic = (pv[r] == vmax && pi[r] + 1u > ic) ? pi[r] + 1u : ic;
                const u64 bal = __ballot(ic != 0);
                u32 winv; int ol;
                if (__popcll(bal) == 1) {
                    ol = (int)__ffsll((long long)bal) - 1;
                    winv = __shfl(ic, ol) - 1u;
                } else {
                    winv = wave_max_u32(ic) - 1u;
                    int m = 0;
#pragma unroll
                    for (int r = 0; r < WPL; ++r)
                        m |= (pv[r] == vmax) & (pi[r] == winv);
                    ol = (int)__ffsll((long long)__ballot(m)) - 1;
                }
                float sxc = 0.f, syc = 0.f, szc = 0.f;
#pragma unroll
                for (int r = 0; r < WPL; ++r) {
                    const int m = (pv[r] == vmax) & (pi[r] == winv);
                    sxc = m ? ex[r] : sxc;
                    syc = m ? ey[r] : syc;
                    szc = m ? ez[r] : szc;
                }
                const float wx = __shfl(sxc, ol);
                const float wy = __shfl(syc, ol);
                const float wz = __shfl(szc, ol);

                if (lane == 0) {
                    wcx[tc] = wx; wcy[tc] = wy; wcz[tc] = wz;
                    if (j == 0) {
                        float* o = out + ((size_t)b * MCENT + (C + tc)) * 3;
                        o[0] = wx; o[1] = wy; o[2] = wz;
                    }
                }
                ++tc;
                if (C + tc >= MCENT || tc >= TMAX) break;

                // pool min-update (bit-exact chain)
#pragma unroll
                for (int r = 0; r < WPL; ++r) {
                    const float dx = __fsub_rn(ex[r], wx);
                    const float dy = __fsub_rn(ey[r], wy);
                    const float dz = __fsub_rn(ez[r], wz);
                    const float s2 = __fmaf_rn(dz, dz,
                                     __fmaf_rn(dx, dx,
                                     __fmul_rn(dy, dy)));
                    pv[r] = fbits(fminf(bitsf(pv[r]), s2));
                }
                // crush owned groups' hidden bounds via the winner
                u32 nlb = 0;
#pragma unroll
                for (int i = 0; i < 4; ++i) {
                    const int gg = 4 * lane + i;
                    const float mx = fmaxf(wx - boxf[gg * 6 + 0], boxf[gg * 6 + 3] - wx);
                    const float my = fmaxf(wy - boxf[gg * 6 + 1], boxf[gg * 6 + 4] - wy);
                    const float mz = fmaxf(wz - boxf[gg * 6 + 2], boxf[gg * 6 + 5] - wz);
                    const float md2 = __fmaf_rn(mz, mz, __fmaf_rn(my, my, __fmul_rn(mx, mx)));
                    cr[i] = fminf(cr[i], md2);
                    const u32 cb = fbits(cr[i]);
                    const u32 bi = third[i] < cb ? third[i] : cb;
                    nlb = bi > nlb ? bi : nlb;
                }
                lb = nlb;
            }
            if (lane == 0) wcnt = tc;
        }
    }
}

// ============================================================================
// Fallback: verbatim R11 champion (static tau, unsorted groups)
// ============================================================================
template<int TOPK>
__global__ __launch_bounds__(THREADS, 1) void fps_kernel(
    const float* __restrict__ xyz,
    float* __restrict__ out,
    u64* __restrict__ slots)
{
    constexpr int POOLW = BPB * NGRP * TOPK;
    constexpr int WPL   = POOLW / 64;

    const int t = threadIdx.x;
    const int b = blockIdx.x >> 3;
    const int j = blockIdx.x & 7;
    const float* base = xyz + (size_t)b * NPTS * 3;
    const int p0 = j * CHUNK;
    const int wave = t >> 6;
    const int lane = t & 63;

    v2f px2[NPAIR], py2[NPAIR], pz2[NPAIR];
    float pd[WPT];
#pragma unroll
    for (int q = 0; q < WPT; ++q) {
        const int p = p0 + q * THREADS + t;
        px2[q >> 1][q & 1] = base[(size_t)p * 3 + 0];
        py2[q >> 1][q & 1] = base[(size_t)p * 3 + 1];
        pz2[q >> 1][q & 1] = base[(size_t)p * 3 + 2];
        pd[q] = 1e10f;
    }

    __shared__ float wcx[TMAX], wcy[TMAX], wcz[TMAX];
    __shared__ int   wcnt;

    if (t == 0) {
        const float cx = base[0], cy = base[1], cz = base[2];
        wcx[0] = cx; wcy[0] = cy; wcz[0] = cz; wcnt = 1;
        if (j == 0) {
            float* o = out + (size_t)b * MCENT * 3;
            o[0] = cx; o[1] = cy; o[2] = cz;
        }
    }

    int C = 0;
    for (int s = 1; ; ++s) {
        __syncthreads();
        const int tn = wcnt;
        C += tn;
        if (C >= MCENT) break;

        for (int tt = 0; tt < tn; ++tt) {
            const float cx = wcx[tt], cy = wcy[tt], cz = wcz[tt];
            const v2f cx2 = { cx, cx }, cy2 = { cy, cy }, cz2 = { cz, cz };
#pragma unroll
            for (int q = 0; q < NPAIR; ++q) {
                const v2f dx2 = px2[q] - cx2;
                const v2f dy2 = py2[q] - cy2;
                const v2f dz2 = pz2[q] - cz2;
                const v2f t0 = dy2 * dy2;
                const v2f t1 = __builtin_elementwise_fma(dx2, dx2, t0);
                const v2f t2 = __builtin_elementwise_fma(dz2, dz2, t1);
                pd[2 * q + 0] = fminf(pd[2 * q + 0], t2.x);
                pd[2 * q + 1] = fminf(pd[2 * q + 1], t2.y);
            }
        }

        u64 k1 = 0, k2 = 0, k3 = 0;
#pragma unroll
        for (int q = 0; q < WPT; ++q) {
            const u64 kk = ((u64)fbits(pd[q]) << 16)
                         | (u64)(0xFFFFu ^ (u32)(p0 + q * THREADS + t));
            if (kk > k1)      { k3 = k2; k2 = k1; k1 = kk; }
            else if (kk > k2) { k3 = k2; k2 = kk; }
            else if (kk > k3) { k3 = kk; }
        }
#pragma unroll
        for (int m = 1; m <= 16; m <<= 1) {
            const u64 o1 = __shfl_xor(k1, m);
            const u64 o2 = __shfl_xor(k2, m);
            if constexpr (TOPK == 2) {
                if (o1 > k1) { k2 = (k1 > o2) ? k1 : o2; k1 = o1; }
                else         { k2 = (k2 > o1) ? k2 : o1; }
            } else {
                const u64 o3 = __shfl_xor(k3, m);
                u64 m1, m2, m3;
                if (o1 > k1) {
                    m1 = o1;
                    if (o2 > k1) { m2 = o2; m3 = (o3 > k1) ? o3 : k1; }
                    else         { m2 = k1; m3 = (o2 > k2) ? o2 : k2; }
                } else {
                    m1 = k1;
                    if (o1 > k2) { m2 = o1; m3 = (o2 > k2) ? o2 : k2; }
                    else         { m2 = k2; m3 = (o1 > k3) ? o1 : k3; }
                }
                k1 = m1; k2 = m2; k3 = m3;
            }
        }

        u64* const bb = slots + ((size_t)(s & 1) * NBATCH + b) * POOLW;
        const u32 tag = (u32)s & 0xFFFFu;

        if ((lane & 31) == 0) {
            const int g = wave * GPW + (lane >> 5);
            u64* const gw = &bb[j * (NGRP * TOPK) + g * TOPK];
            __hip_atomic_store(&gw[0], (k1 << 16) | tag, __ATOMIC_RELAXED, __HIP_MEMORY_SCOPE_AGENT);
            __hip_atomic_store(&gw[1], (k2 << 16) | tag, __ATOMIC_RELAXED, __HIP_MEMORY_SCOPE_AGENT);
            if constexpr (TOPK == 3)
                __hip_atomic_store(&gw[2], (k3 << 16) | tag, __ATOMIC_RELAXED, __HIP_MEMORY_SCOPE_AGENT);
        }

        if (wave == 0) {
            u64 w[WPL]; int ok;
            do {
#pragma unroll
                for (int r = 0; r < WPL; ++r)
                    w[r] = __hip_atomic_load(&bb[lane + 64 * r], __ATOMIC_RELAXED, __HIP_MEMORY_SCOPE_AGENT);
                ok = 1;
#pragma unroll
                for (int r = 0; r < WPL; ++r)
                    ok &= ((u32)(w[r] & 0xFFFFull) == tag);
            } while (!__all(ok));

            u32 pv[WPL], pi[WPL];
            float ex[WPL], ey[WPL], ez[WPL];
#pragma unroll
            for (int r = 0; r < WPL; ++r) {
                pv[r] = (u32)(w[r] >> 32);
                pi[r] = ((u32)w[r] >> 16) & 0xFFFFu;
                const int gi = (int)(0xFFFFu ^ pi[r]);
                ex[r] = base[(size_t)gi * 3 + 0];
                ey[r] = base[(size_t)gi * 3 + 1];
                ez[r] = base[(size_t)gi * 3 + 2];
            }

            u32 tl = 0;
#pragma unroll
            for (int r = 0; r < WPL; ++r) {
                const int rank = ((lane % TOPK) + (64 % TOPK) * r) % TOPK;
                if (rank == TOPK - 1) tl = pv[r] > tl ? pv[r] : tl;
            }
            const u32 tauv = wave_max_u32(tl);

            int tc = 0;
            while (1) {
                u32 lv = 0;
#pragma unroll
                for (int r = 0; r < WPL; ++r) lv = pv[r] > lv ? pv[r] : lv;
                const u32 vmax = wave_max_u32(lv);
                if (tc > 0 && vmax <= tauv) break;

                u32 ic = 0;
#pragma unroll
                for (int r = 0; r < WPL; ++r)
                    ic = (pv[r] == vmax && pi[r] + 1u > ic) ? pi[r] + 1u : ic;
                const u64 bal = __ballot(ic != 0);
                u32 winv; int ol;
                if (__popcll(bal) == 1) {
                    ol = (int)__ffsll((long long)bal) - 1;
                    winv = __shfl(ic, ol) - 1u;
                } else {
                    winv = wave_max_u32(ic) - 1u;
                    int m = 0;
#pragma unroll
                    for (int r = 0; r < WPL; ++r)
                        m |= (pv[r] == vmax) & (pi[r] == winv);
                    ol = (int)__ffsll((long long)__ballot(m)) - 1;
                }

                float sxc = 0.f, syc = 0.f, szc = 0.f;
#pragma unroll
                for (int r = 0; r < WPL; ++r) {
                    const int m = (pv[r] == vmax) & (pi[r] == winv);
                    sxc = m ? ex[r] : sxc;
                    syc = m ? ey[r] : syc;
                    szc = m ? ez[r] : szc;
                }
                const float wx = __shfl(sxc, ol);
                const float wy = __shfl(syc, ol);
                const float wz = __shfl(szc, ol);

                if (lane == 0) {
                    wcx[tc] = wx; wcy[tc] = wy; wcz[tc] = wz;
                    if (j == 0) {
                        float* o = out + ((size_t)b * MCENT + (C + tc)) * 3;
                        o[0] = wx; o[1] = wy; o[2] = wz;
                    }
                }
                ++tc;
                if (C + tc >= MCENT || tc >= TMAX) break;

#pragma unroll
                for (int r = 0; r < WPL; ++r) {
                    const float dx = __fsub_rn(ex[r], wx);
                    const float dy = __fsub_rn(ey[r], wy);
                    const float dz = __fsub_rn(ez[r], wz);
                    const float s2 = __fmaf_rn(dz, dz,
                                     __fmaf_rn(dx, dx,
                                     __fmul_rn(dy, dy)));
                    pv[r] = fbits(fminf(bitsf(pv[r]), s2));
                }
            }
            if (lane == 0) wcnt = tc;
        }
    }
}

extern "C" void kernel_launch(void* const* d_in, const int* in_sizes, int n_in,
                              void* d_out, int out_size, void* d_ws, size_t ws_size,
                              hipStream_t stream) {
    const float* xyz = (const float*)d_in[0];
    float* out = (float*)d_out;
    u64* slots = (u64*)d_ws;

    // spatial: pools 2x32x768x8 = 384 KiB + boxes 32x512x8 = 128 KiB
    const size_t need_sp = (size_t)2 * NBATCH * (BPB * NGRP * 3) * sizeof(u64)
                         + (size_t)NBATCH * (GTOT * 2) * sizeof(u64);
    const size_t need3 = (size_t)2 * NBATCH * (BPB * NGRP * 3) * sizeof(u64);
    if (ws_size >= need_sp) {
        fps_spatial<<<dim3(NBATCH * BPB), dim3(THREADS), 0, stream>>>(xyz, out, slots);
    } else if (ws_size >= need3) {
        fps_kernel<3><<<dim3(NBATCH * BPB), dim3(THREADS), 0, stream>>>(xyz, out, slots);
    } else {
        fps_kernel<2><<<dim3(NBATCH * BPB), dim3(THREADS), 0, stream>>>(xyz, out, slots);
    }
}